// Round 1
// baseline (131.145 us; speedup 1.0000x reference)
//
#include <hip/hip_runtime.h>
#include <stdint.h>

// GraphConvolution: out = D^-1 (A+I) (X W) + b
//   X: [8192][256] f32, A: [8192][8192] f32, W: [256][128] f32, b: [128] f32
// Strategy: bf16 MFMA for the 17.2 GFLOP A@(XW) (memory-bound on adj, 256 MB),
// K-split 4 with deterministic two-stage reduction. Row sums of A fused into
// the MFMA kernel (adj is read exactly once from HBM).

#define NROW 8192
#define FIN 256
#define FOUT 128
#define KSPLIT 4
#define KCH (NROW / KSPLIT)  // 2048

typedef __attribute__((ext_vector_type(8))) short bf16x8;
typedef __attribute__((ext_vector_type(4))) float f32x4;

static __device__ __forceinline__ unsigned short f2bf(float x) {
  // round-to-nearest-even f32 -> bf16 (no NaN in this data)
  unsigned u = __builtin_bit_cast(unsigned, x);
  u = (u + 0x7FFFu + ((u >> 16) & 1u)) >> 16;
  return (unsigned short)u;
}

// ---------------- Kernel 1: support = X @ W (f32) + bf16 transposed copy ----
__global__ __launch_bounds__(256) void k_support(
    const float* __restrict__ input, const float* __restrict__ weight,
    float* __restrict__ support, unsigned short* __restrict__ supportT) {
  __shared__ __align__(16) float in_lds[16 * FIN];         // 16 KB
  __shared__ __align__(16) float tr_lds[16 * (FOUT + 4)];  // padded, 8.4 KB
  const int t = threadIdx.x;
  const int rbase = blockIdx.x * 16;  // 512 blocks x 16 rows
  const float* src = input + (size_t)rbase * FIN;
#pragma unroll
  for (int c = 0; c < 4; ++c) {
    const int idx = c * 1024 + t * 4;
    *(float4*)&in_lds[idx] = *(const float4*)&src[idx];
  }
  __syncthreads();
  const int j = t & 127;
  const int rg = t >> 7;  // 0..1, 8 rows each
  float acc[8] = {0.f, 0.f, 0.f, 0.f, 0.f, 0.f, 0.f, 0.f};
  for (int f = 0; f < FIN; f += 4) {
    const float w0 = weight[(f + 0) * FOUT + j];
    const float w1 = weight[(f + 1) * FOUT + j];
    const float w2 = weight[(f + 2) * FOUT + j];
    const float w3 = weight[(f + 3) * FOUT + j];
#pragma unroll
    for (int r = 0; r < 8; ++r) {
      const float4 iv = *(const float4*)&in_lds[(rg * 8 + r) * FIN + f];
      acc[r] += iv.x * w0 + iv.y * w1 + iv.z * w2 + iv.w * w3;
    }
  }
#pragma unroll
  for (int r = 0; r < 8; ++r) {
    const int row = rbase + rg * 8 + r;
    support[(size_t)row * FOUT + j] = acc[r];
    tr_lds[(rg * 8 + r) * (FOUT + 4) + j] = acc[r];
  }
  __syncthreads();
  // transposed bf16 write: supportT[n][k], k contiguous
  const int r = t & 15, g = t >> 4;  // r: row-in-tile, g: 0..15
#pragma unroll
  for (int jj = 0; jj < 8; ++jj) {
    const int jc = jj * 16 + g;
    const float v = tr_lds[r * (FOUT + 4) + jc];
    supportT[(size_t)jc * NROW + rbase + r] = f2bf(v);
  }
}

// ---------------- Kernel 2: partial[ks] = A[:, ksplit] @ support, + rowsums -
// Block: 512 thr = 8 waves; wave (rg,cg): rows rg*16..+16, cols cg*64..+64.
// Per K-step(32): A direct global->reg fp32->bf16; B from LDS (XOR-swizzled).
__global__ __launch_bounds__(512, 4) void k_spmm(
    const float* __restrict__ adj, const unsigned short* __restrict__ supportT,
    float* __restrict__ partial, float* __restrict__ degp) {
  __shared__ __align__(16) unsigned char bT[FOUT * 64];  // 128 rows x 64 B = 8 KB
  const int t = threadIdx.x;
  const int w = t >> 6, l = t & 63;
  const int rb = blockIdx.x >> 2;  // 0..127
  const int ks = blockIdx.x & 3;   // 0..3
  const int rbase = rb * 64;
  const int kbase = ks * KCH;
  const int rg = w >> 1, cg = w & 1;
  const int l15 = l & 15, kg = l >> 4;

  // LDS staging: thread t handles supportT row sn, 16B unit su; swizzle unit.
  const int sn = t >> 2;
  const int su = t & 3;
  const int sup = su ^ ((sn >> 1) & 3);
  const uint4* sgp = (const uint4*)(supportT + (size_t)sn * NROW + kbase + su * 8);
  uint4* slp = (uint4*)(bT + sn * 64 + sup * 16);

  // A: lane reads adj[row = rbase+rg*16+l15][k = kbase + kg*8 + e], e=0..7
  const int arow = rbase + rg * 16 + l15;
  const float* aptr = adj + (size_t)arow * NROW + kbase + kg * 8;

  f32x4 acc[4] = {};
  float rs = 0.f;

  for (int s = 0; s < KCH / 32; ++s) {
    const float4 a0 = *(const float4*)(aptr + s * 32);
    const float4 a1 = *(const float4*)(aptr + s * 32 + 4);
    __syncthreads();           // previous iter's B reads done
    *slp = sgp[s * 4];         // stage 64 B/row chunk (32 k) of supportT
    __syncthreads();           // staging visible
    rs += ((a0.x + a0.y) + (a0.z + a0.w)) + ((a1.x + a1.y) + (a1.z + a1.w));
    bf16x8 af;
    af[0] = (short)f2bf(a0.x); af[1] = (short)f2bf(a0.y);
    af[2] = (short)f2bf(a0.z); af[3] = (short)f2bf(a0.w);
    af[4] = (short)f2bf(a1.x); af[5] = (short)f2bf(a1.y);
    af[6] = (short)f2bf(a1.z); af[7] = (short)f2bf(a1.w);
#pragma unroll
    for (int tt = 0; tt < 4; ++tt) {
      const int n = cg * 64 + tt * 16 + l15;
      const int up = kg ^ ((n >> 1) & 3);
      const bf16x8 bfv = *(const bf16x8*)(bT + n * 64 + up * 16);
      acc[tt] = __builtin_amdgcn_mfma_f32_16x16x32_bf16(af, bfv, acc[tt], 0, 0, 0);
    }
  }

  // rowsum: lane groups (kg) of the same row combine
  rs += __shfl_xor(rs, 16, 64);
  rs += __shfl_xor(rs, 32, 64);
  if (cg == 0 && l < 16)
    degp[ks * NROW + rbase + rg * 16 + l] = rs;

  // C/D layout (verified m89/m91): col = lane&15, row = (lane>>4)*4 + reg
  float* pout = partial + (size_t)ks * NROW * FOUT;
  const int prow = rbase + rg * 16 + kg * 4;
  const int pcol = cg * 64 + l15;
#pragma unroll
  for (int tt = 0; tt < 4; ++tt)
#pragma unroll
    for (int q = 0; q < 4; ++q)
      pout[(size_t)(prow + q) * FOUT + pcol + tt * 16] = acc[tt][q];
}

// ---------------- Kernel 3: combine partials, scale by 1/deg, add bias ------
__global__ __launch_bounds__(256) void k_final(
    const float* __restrict__ partial, const float* __restrict__ degp,
    const float* __restrict__ support, const float* __restrict__ bias,
    float* __restrict__ out) {
  const int idx = blockIdx.x * 256 + threadIdx.x;  // 262144 threads x 4 elems
  const int e = idx * 4;
  const int i = e >> 7;
  const int j = e & 127;
  float d = 1.0f + degp[i] + degp[NROW + i] + degp[2 * NROW + i] + degp[3 * NROW + i];
  float dinv = 1.0f / d;
  if (dinv != dinv) dinv = 0.f;  // mimic reference NaN-zeroing
  const float4 p0 = *(const float4*)&partial[e];
  const float4 p1 = *(const float4*)&partial[(1u << 20) + e];
  const float4 p2 = *(const float4*)&partial[(2u << 20) + e];
  const float4 p3 = *(const float4*)&partial[(3u << 20) + e];
  const float4 sv = *(const float4*)&support[e];
  const float4 bv = *(const float4*)&bias[j];
  float4 o;
  o.x = (p0.x + p1.x + p2.x + p3.x + sv.x) * dinv + bv.x;
  o.y = (p0.y + p1.y + p2.y + p3.y + sv.y) * dinv + bv.y;
  o.z = (p0.z + p1.z + p2.z + p3.z + sv.z) * dinv + bv.z;
  o.w = (p0.w + p1.w + p2.w + p3.w + sv.w) * dinv + bv.w;
  *(float4*)&out[e] = o;
}

extern "C" void kernel_launch(void* const* d_in, const int* in_sizes, int n_in,
                              void* d_out, int out_size, void* d_ws, size_t ws_size,
                              hipStream_t stream) {
  const float* input  = (const float*)d_in[0];
  const float* adj    = (const float*)d_in[1];
  const float* weight = (const float*)d_in[2];
  const float* bias   = (const float*)d_in[3];
  float* out = (float*)d_out;
  float* ws = (float*)d_ws;
  // ws layout (f32 units): support 1M | partial 4x1M | degp 32K | supportT(bf16) 1M
  float* support = ws;
  float* partial = ws + (1u << 20);
  float* degp    = ws + (5u << 20);
  unsigned short* supportT = (unsigned short*)(degp + NROW * KSPLIT);
  // total ws use ~23.3 MB

  k_support<<<NROW / 16, 256, 0, stream>>>(input, weight, support, supportT);
  k_spmm<<<(NROW / 64) * KSPLIT, 512, 0, stream>>>(adj, supportT, partial, degp);
  k_final<<<(NROW * FOUT / 4) / 256, 256, 0, stream>>>(partial, degp, support, bias, out);
}